// Round 6
// baseline (128.395 us; speedup 1.0000x reference)
//
#include <hip/hip_runtime.h>
#include <hip/hip_bf16.h>

// Problem constants
#define BB    16
#define CREF  256
#define CINC  256
#define COUTC 256
#define KKN   4
#define HH    56
#define WWW   56
#define HIDDEN 65
#define NPIX  3136          // 56*56
#define PPIX  3364          // 58*58 padded
#define TEMP  34.0f

typedef __bf16 bf16x8 __attribute__((ext_vector_type(8)));
typedef float  f32x4  __attribute__((ext_vector_type(4)));

// ---------------- ws layout (bytes) ----------------
#define WS_ATTN   0
#define WS_AGGB   4096
#define WS_POOL   24576
#define WS_AGGW   65536      // 16*2*8*36864 elems bf16 = 18,874,368 B  [b][ch][cb8][tap][cing][cout128][cin8]
#define WS_XPAD   19005440   // 16*3364*256*2 = 27,557,888 (+slack for staging overread)

// conv LDS sizing
#define XBUF  40960          // [cg4][row10][col64][16B]
#define ABUF  73728          // [tap9][cing4][cout128][16B]
#define LDS_TOT (2*XBUF + ABUF)   // 155,648 B

// ---------- 1. adaptive avg pool (one wave per (b,c)) + xpad border zeroing ----------
__global__ void pool_k(const float* __restrict__ ref, float* __restrict__ pooled,
                       __bf16* __restrict__ xpad) {
    int wid = threadIdx.x >> 6, lane = threadIdx.x & 63;
    int gw = blockIdx.x * 4 + wid;            // 0..4095 = b*256+c
    const float4* r4 = reinterpret_cast<const float4*>(ref) + (size_t)gw * 784;
    float s = 0.f;
    for (int i = lane; i < 784; i += 64) {
        float4 v = r4[i];
        s += v.x + v.y + v.z + v.w;
    }
    for (int o = 32; o; o >>= 1) s += __shfl_xor(s, o);
    if (lane == 0) pooled[gw] = s * (1.0f / (float)NPIX);

    // border zeroing: 16 b * 228 border positions, 512B rows
    if (gw < 3648) {
        int b = gw / 228, i = gw % 228;
        int ph, pw;
        if (i < 58)       { ph = 0;        pw = i; }
        else if (i < 116) { ph = 57;       pw = i - 58; }
        else if (i < 172) { ph = i - 115;  pw = 0; }
        else              { ph = i - 171;  pw = 57; }
        uint2* dst = (uint2*)(xpad + ((size_t)b * PPIX + ph * 58 + pw) * 256);
        dst[lane] = (uint2){0u, 0u};
    }
}

// ---------- 2. attention + agg bias: one block per batch sample ----------
__global__ void attn_k(const float* __restrict__ pooled, const float* __restrict__ fc1w,
                       const float* __restrict__ fc2w, const float* __restrict__ fc2b,
                       const float* __restrict__ bias,
                       float* __restrict__ attn, float* __restrict__ aggb) {
    int b = blockIdx.x;
    int t = threadIdx.x;
    __shared__ float sh[HIDDEN + 7];
    __shared__ float sl[KKN];
    __shared__ float sa[KKN];
    const float* prow = pooled + b * CREF;
    {
        int j = t >> 2, sub = t & 3;
        const float4* w4 = (const float4*)(fc1w + j * CREF + sub * 64);
        const float4* p4 = (const float4*)(prow + sub * 64);
        float s = 0.f;
#pragma unroll
        for (int k = 0; k < 16; ++k) {
            float4 w = w4[k], p = p4[k];
            s += w.x * p.x + w.y * p.y + w.z * p.z + w.w * p.w;
        }
        s += __shfl_xor(s, 1); s += __shfl_xor(s, 2);
        if (sub == 0) sh[j] = fmaxf(s, 0.f);
    }
    if (t < 4) {   // j = 64
        const float4* w4 = (const float4*)(fc1w + 64 * CREF + t * 64);
        const float4* p4 = (const float4*)(prow + t * 64);
        float s = 0.f;
#pragma unroll
        for (int k = 0; k < 16; ++k) {
            float4 w = w4[k], p = p4[k];
            s += w.x * p.x + w.y * p.y + w.z * p.z + w.w * p.w;
        }
        s += __shfl_xor(s, 1); s += __shfl_xor(s, 2);
        if (t == 0) sh[64] = fmaxf(s, 0.f);
    }
    __syncthreads();
    if (t < KKN) {
        float s = fc2b[t];
        for (int j = 0; j < HIDDEN; ++j) s += sh[j] * fc2w[t * HIDDEN + j];
        sl[t] = s * (1.0f / TEMP);
    }
    __syncthreads();
    if (t == 0) {
        float m = fmaxf(fmaxf(sl[0], sl[1]), fmaxf(sl[2], sl[3]));
        float e0 = expf(sl[0] - m), e1 = expf(sl[1] - m);
        float e2 = expf(sl[2] - m), e3 = expf(sl[3] - m);
        float inv = 1.f / (e0 + e1 + e2 + e3);
        sa[0] = e0 * inv; sa[1] = e1 * inv; sa[2] = e2 * inv; sa[3] = e3 * inv;
        attn[b * 4 + 0] = sa[0]; attn[b * 4 + 1] = sa[1];
        attn[b * 4 + 2] = sa[2]; attn[b * 4 + 3] = sa[3];
    }
    __syncthreads();
    {
        float s = 0.f;
#pragma unroll
        for (int k = 0; k < KKN; ++k) s += sa[k] * bias[k * COUTC + t];
        aggb[b * COUTC + t] = s;
    }
}

// ---------- 3. blend weights -> bf16 [b][ch][cb8][tap][cing][cout128][cin8] ----------
// grid (32 cout-blocks, 8 cb8), block 256 = (cout 8) x (cr 32)
__global__ void aggw_k(const float* __restrict__ attn, const float* __restrict__ weight,
                       __bf16* __restrict__ aggw) {
    __shared__ float s_attn[64];
    int t = threadIdx.x;
    int co = t >> 5, cr = t & 31;
    int cout = blockIdx.x * 8 + co;       // 0..255
    int cb8 = blockIdx.y;                 // 0..7
    int cin = cb8 * 32 + cr;
    if (t < 64) s_attn[t] = attn[t];
    __syncthreads();
    float w[4][9];
#pragma unroll
    for (int k = 0; k < 4; ++k) {
        const float* wp = weight + ((size_t)(k * 256 + cout) * 256 + cin) * 9;
#pragma unroll
        for (int tp = 0; tp < 9; ++tp) w[k][tp] = wp[tp];
    }
    int ch = cout >> 7, coutl = cout & 127;
    int cing = cr >> 3, cinr = cr & 7;
    for (int b = 0; b < BB; ++b) {
        float a0 = s_attn[b * 4 + 0], a1 = s_attn[b * 4 + 1];
        float a2 = s_attn[b * 4 + 2], a3 = s_attn[b * 4 + 3];
#pragma unroll
        for (int tap = 0; tap < 9; ++tap) {
            float v = a0 * w[0][tap] + a1 * w[1][tap] + a2 * w[2][tap] + a3 * w[3][tap];
            size_t e = (size_t)((b * 2 + ch) * 8 + cb8) * 36864 +
                       (tap * 4 + cing) * 1024 + coutl * 8 + cinr;
            aggw[e] = (__bf16)v;
        }
    }
}

// ---------- 4. x -> padded NHWC bf16 (interior, tiled transpose) ----------
__global__ void xpad_int_k(const float* __restrict__ x, __bf16* __restrict__ xpad) {
    __shared__ float tile[64][65];
    int pt = blockIdx.x;      // 0..48 pixel tile (64 px)
    int cg = blockIdx.y;      // 0..3 cin group (64 cins)
    int b  = blockIdx.z;
    int q = threadIdx.x >> 6, l = threadIdx.x & 63;
    for (int k = 0; k < 16; ++k) {
        int cl = q * 16 + k;
        tile[cl][l] = x[((size_t)(b * 256 + cg * 64 + cl)) * NPIX + pt * 64 + l];
    }
    __syncthreads();
    for (int k = 0; k < 16; ++k) {
        int pl = q * 16 + k;
        int pixel = pt * 64 + pl;
        int h = pixel / 56, w = pixel - h * 56;
        xpad[(((size_t)b * PPIX + (h + 1) * 58 + (w + 1)) * 256) + cg * 64 + l] =
            (__bf16)tile[l][pl];
    }
}

// ---------- 5. conv: implicit GEMM, A and X both LDS-staged ----------
// block: 128 couts x 8 output rows; 8 waves, wave = 128 couts x 1 row (Mr=8, Nr=4).
// LDS: X dbuf 2x40KB ([cg4][row10][col64][16B]) + A 73.7KB ([tap9][cing4][cout128][16B]).
// Schedule: 2 phases/K-step with COUNTED vmcnt (T4) + raw barriers; X loads stay in
// flight across the phase-A barrier (vmcnt(5)); setprio(1) around MFMA clusters (T5).
__global__ __launch_bounds__(512, 2) void conv_k(const __bf16* __restrict__ xpad,
                                                 const __bf16* __restrict__ aggw,
                                                 const float* __restrict__ aggb,
                                                 float* __restrict__ out) {
    extern __shared__ __attribute__((aligned(16))) char smem[];
    char* xs = smem;                 // 2 X buffers
    char* as = smem + 2 * XBUF;      // A buffer

    const int orig = blockIdx.x;
    const int logical = (orig & 7) * 28 + (orig >> 3);   // bijective, 224 = 8*28
    const int b  = logical / 14;
    const int r  = logical - b * 14;
    const int rp = r >> 1;            // 0..6 row-octet
    const int ch = r & 1;             // cout half
    const int tid = threadIdx.x;
    const int wid = tid >> 6, lane = tid & 63;
    const int l15 = lane & 15, l4 = lane >> 4;
    const int h0 = rp * 8;            // top padded row staged (rows h0..h0+9)

    const char* xb  = (const char*)xpad + (size_t)b * PPIX * 512;
    const char* awb = (const char*)aggw + (size_t)((b * 2 + ch) * 8) * ABUF;

    f32x4 acc[8][4];
#pragma unroll
    for (int m = 0; m < 8; ++m)
#pragma unroll
        for (int n = 0; n < 4; ++n) acc[m][n] = (f32x4){0.f, 0.f, 0.f, 0.f};

    // stage X K-block c into buffer buf: 40 x 1KB, 5 per wave
    auto XSTAGE = [&](int buf, int c) {
#pragma unroll
        for (int j = 0; j < 5; ++j) {
            int k = wid * 5 + j;             // 0..39
            int cg = k / 10, row = k - cg * 10;
            const char* src = xb + (size_t)((h0 + row) * 58 + lane) * 512 + c * 64 + cg * 16;
            __builtin_amdgcn_global_load_lds(
                (const __attribute__((address_space(1))) void*)src,
                (__attribute__((address_space(3))) void*)(xs + buf * XBUF + k * 1024),
                16, 0, 0);
        }
    };
    // stage A slots [k0, k0+8n) for K-block c (n loads per wave)
    auto ASTAGE = [&](int k0, int n, int c) {
        for (int j = 0; j < n; ++j) {
            int k = k0 + wid * n + j;
            const char* src = awb + (size_t)c * ABUF + k * 1024 + lane * 16;
            __builtin_amdgcn_global_load_lds(
                (const __attribute__((address_space(1))) void*)src,
                (__attribute__((address_space(3))) void*)(as + k * 1024),
                16, 0, 0);
        }
    };
    // compute taps [t0, t1) against X buffer buf
    auto COMPUTE = [&](int t0, int t1, int buf) {
        for (int t = t0; t < t1; ++t) {
            int kh = t / 3, kw = t - kh * 3;
            bf16x8 a[8];
#pragma unroll
            for (int m = 0; m < 8; ++m)
                a[m] = *(const bf16x8*)(as + (t * 4 + l4) * 2048 + (m * 16 + l15) * 16);
#pragma unroll
            for (int nf = 0; nf < 4; ++nf) {
                bf16x8 bb = *(const bf16x8*)(xs + buf * XBUF +
                    (((l4 * 10 + wid + kh) * 64) + nf * 16 + l15 + kw) * 16);
#pragma unroll
                for (int m = 0; m < 8; ++m)
                    acc[m][nf] = __builtin_amdgcn_mfma_f32_16x16x32_bf16(a[m], bb, acc[m][nf], 0, 0, 0);
            }
        }
    };

    // prologue: full X[0] + full A[0], one-time full drain
    XSTAGE(0, 0);
    ASTAGE(0, 9, 0);                 // 72 slots, 9 per wave
    __syncthreads();

    int cur = 0;
    for (int c = 0; c < 8; ++c) {
        // ---- phase A: taps 0..3 (A slots 0..31 = A-lo(c)) ----
        if (c > 0) ASTAGE(32, 5, c);          // A-hi(c), needed after this barrier
        if (c < 7) XSTAGE(cur ^ 1, c + 1);    // X(c+1), needed after NEXT barrier
        __builtin_amdgcn_s_setprio(1);
        COMPUTE(0, 4, cur);
        __builtin_amdgcn_s_setprio(0);
        // wait A-hi(c) only; leave the 5 X(c+1) loads in flight across the barrier
        if (c < 7) { asm volatile("s_waitcnt vmcnt(5)" ::: "memory"); }
        else       { asm volatile("s_waitcnt vmcnt(0)" ::: "memory"); }
        __builtin_amdgcn_s_barrier();
        __builtin_amdgcn_sched_barrier(0);
        // ---- phase B: taps 4..8 (A slots 32..71 = A-hi(c)) ----
        if (c < 7) ASTAGE(0, 4, c + 1);       // A-lo(c+1)
        __builtin_amdgcn_s_setprio(1);
        COMPUTE(4, 9, cur);
        __builtin_amdgcn_s_setprio(0);
        if (c < 7) {
            // X(c+1) + A-lo(c+1) both needed next phase: drain (issued 1-2 phases ago)
            asm volatile("s_waitcnt vmcnt(0)" ::: "memory");
            __builtin_amdgcn_s_barrier();
            __builtin_amdgcn_sched_barrier(0);
        }
        cur ^= 1;
    }

    const int row = rp * 8 + wid;             // output row
#pragma unroll
    for (int m = 0; m < 8; ++m) {
#pragma unroll
        for (int i = 0; i < 4; ++i) {
            int cout = ch * 128 + m * 16 + l4 * 4 + i;
            float bv = aggb[b * COUTC + cout];
            float* op = out + ((size_t)(b * COUTC + cout) * NPIX + row * 56);
#pragma unroll
            for (int nf = 0; nf < 3; ++nf)
                __builtin_nontemporal_store(acc[m][nf][i] + bv, op + nf * 16 + l15);
            if (l15 < 8)
                __builtin_nontemporal_store(acc[m][3][i] + bv, op + 48 + l15);
        }
    }
}

extern "C" void kernel_launch(void* const* d_in, const int* in_sizes, int n_in,
                              void* d_out, int out_size, void* d_ws, size_t ws_size,
                              hipStream_t stream) {
    (void)in_sizes; (void)n_in; (void)out_size; (void)ws_size;
    const float* ref    = (const float*)d_in[0];
    const float* x      = (const float*)d_in[1];
    const float* fc1w   = (const float*)d_in[2];
    const float* fc2w   = (const float*)d_in[3];
    const float* fc2b   = (const float*)d_in[4];
    const float* weight = (const float*)d_in[5];
    const float* bias   = (const float*)d_in[6];
    float* out = (float*)d_out;
    char* ws = (char*)d_ws;

    float*  attn   = (float*)(ws + WS_ATTN);
    float*  aggb   = (float*)(ws + WS_AGGB);
    float*  pooled = (float*)(ws + WS_POOL);
    __bf16* aggw   = (__bf16*)(ws + WS_AGGW);
    __bf16* xpad   = (__bf16*)(ws + WS_XPAD);

    // allow >64KB dynamic LDS for conv_k (deterministic, capture-safe host call)
    hipFuncSetAttribute((const void*)conv_k,
                        hipFuncAttributeMaxDynamicSharedMemorySize, LDS_TOT);

    pool_k<<<1024, 256, 0, stream>>>(ref, pooled, xpad);
    attn_k<<<16, 256, 0, stream>>>(pooled, fc1w, fc2w, fc2b, bias, attn, aggb);
    aggw_k<<<dim3(32, 8), 256, 0, stream>>>(attn, weight, aggw);
    xpad_int_k<<<dim3(49, 4, 16), 256, 0, stream>>>(x, xpad);
    conv_k<<<224, 512, LDS_TOT, stream>>>(xpad, aggw, aggb, out);
}

// Round 7
// 106.242 us; speedup vs baseline: 1.2085x; 1.2085x over previous
//
#include <hip/hip_runtime.h>
#include <hip/hip_bf16.h>

// Problem constants
#define BB    16
#define CREF  256
#define CINC  256
#define COUTC 256
#define KKN   4
#define HH    56
#define WWW   56
#define HIDDEN 65
#define NPIX  3136          // 56*56
#define PPIX  3364          // 58*58 padded
#define TEMP  34.0f

typedef __bf16 bf16x8 __attribute__((ext_vector_type(8)));
typedef float  f32x4  __attribute__((ext_vector_type(4)));

// ---------------- ws layout (bytes) ----------------
#define WS_ATTN   0
#define WS_AGGB   4096
#define WS_POOL   24576
#define WS_AGGW   65536      // 16*2*8*36864 elems bf16 = 18,874,368 B  [b][ch][cb8][tap][cing][cout128][cin8]
#define WS_XPAD   19005440   // 16*3364*256*2 = 27,557,888 (+slack for staging overread)

// conv LDS sizing
#define XBUF  40960          // [cg4][row10][col64][16B]
#define ABUF  73728          // [tap9][cing4][cout128][16B]
#define LDS_TOT (2*XBUF + ABUF)   // 155,648 B

// ---------- 1. adaptive avg pool (one wave per (b,c)) + xpad border zeroing ----------
__global__ void pool_k(const float* __restrict__ ref, float* __restrict__ pooled,
                       __bf16* __restrict__ xpad) {
    int wid = threadIdx.x >> 6, lane = threadIdx.x & 63;
    int gw = blockIdx.x * 4 + wid;            // 0..4095 = b*256+c
    const float4* r4 = reinterpret_cast<const float4*>(ref) + (size_t)gw * 784;
    float s = 0.f;
    for (int i = lane; i < 784; i += 64) {
        float4 v = r4[i];
        s += v.x + v.y + v.z + v.w;
    }
    for (int o = 32; o; o >>= 1) s += __shfl_xor(s, o);
    if (lane == 0) pooled[gw] = s * (1.0f / (float)NPIX);

    // border zeroing: 16 b * 228 border positions, 512B rows
    if (gw < 3648) {
        int b = gw / 228, i = gw % 228;
        int ph, pw;
        if (i < 58)       { ph = 0;        pw = i; }
        else if (i < 116) { ph = 57;       pw = i - 58; }
        else if (i < 172) { ph = i - 115;  pw = 0; }
        else              { ph = i - 171;  pw = 57; }
        uint2* dst = (uint2*)(xpad + ((size_t)b * PPIX + ph * 58 + pw) * 256);
        dst[lane] = (uint2){0u, 0u};
    }
}

// ---------- 2. attention + agg bias: one block per batch sample ----------
__global__ void attn_k(const float* __restrict__ pooled, const float* __restrict__ fc1w,
                       const float* __restrict__ fc2w, const float* __restrict__ fc2b,
                       const float* __restrict__ bias,
                       float* __restrict__ attn, float* __restrict__ aggb) {
    int b = blockIdx.x;
    int t = threadIdx.x;
    __shared__ float sh[HIDDEN + 7];
    __shared__ float sl[KKN];
    __shared__ float sa[KKN];
    const float* prow = pooled + b * CREF;
    {
        int j = t >> 2, sub = t & 3;
        const float4* w4 = (const float4*)(fc1w + j * CREF + sub * 64);
        const float4* p4 = (const float4*)(prow + sub * 64);
        float s = 0.f;
#pragma unroll
        for (int k = 0; k < 16; ++k) {
            float4 w = w4[k], p = p4[k];
            s += w.x * p.x + w.y * p.y + w.z * p.z + w.w * p.w;
        }
        s += __shfl_xor(s, 1); s += __shfl_xor(s, 2);
        if (sub == 0) sh[j] = fmaxf(s, 0.f);
    }
    if (t < 4) {   // j = 64
        const float4* w4 = (const float4*)(fc1w + 64 * CREF + t * 64);
        const float4* p4 = (const float4*)(prow + t * 64);
        float s = 0.f;
#pragma unroll
        for (int k = 0; k < 16; ++k) {
            float4 w = w4[k], p = p4[k];
            s += w.x * p.x + w.y * p.y + w.z * p.z + w.w * p.w;
        }
        s += __shfl_xor(s, 1); s += __shfl_xor(s, 2);
        if (t == 0) sh[64] = fmaxf(s, 0.f);
    }
    __syncthreads();
    if (t < KKN) {
        float s = fc2b[t];
        for (int j = 0; j < HIDDEN; ++j) s += sh[j] * fc2w[t * HIDDEN + j];
        sl[t] = s * (1.0f / TEMP);
    }
    __syncthreads();
    if (t == 0) {
        float m = fmaxf(fmaxf(sl[0], sl[1]), fmaxf(sl[2], sl[3]));
        float e0 = expf(sl[0] - m), e1 = expf(sl[1] - m);
        float e2 = expf(sl[2] - m), e3 = expf(sl[3] - m);
        float inv = 1.f / (e0 + e1 + e2 + e3);
        sa[0] = e0 * inv; sa[1] = e1 * inv; sa[2] = e2 * inv; sa[3] = e3 * inv;
        attn[b * 4 + 0] = sa[0]; attn[b * 4 + 1] = sa[1];
        attn[b * 4 + 2] = sa[2]; attn[b * 4 + 3] = sa[3];
    }
    __syncthreads();
    {
        float s = 0.f;
#pragma unroll
        for (int k = 0; k < KKN; ++k) s += sa[k] * bias[k * COUTC + t];
        aggb[b * COUTC + t] = s;
    }
}

// ---------- 3. blend weights -> bf16 [b][ch][cb8][tap][cing][cout128][cin8] ----------
// grid (32 cout-blocks, 8 cb8), block 256 = (cout 8) x (cr 32)
__global__ void aggw_k(const float* __restrict__ attn, const float* __restrict__ weight,
                       __bf16* __restrict__ aggw) {
    __shared__ float s_attn[64];
    int t = threadIdx.x;
    int co = t >> 5, cr = t & 31;
    int cout = blockIdx.x * 8 + co;       // 0..255
    int cb8 = blockIdx.y;                 // 0..7
    int cin = cb8 * 32 + cr;
    if (t < 64) s_attn[t] = attn[t];
    __syncthreads();
    float w[4][9];
#pragma unroll
    for (int k = 0; k < 4; ++k) {
        const float* wp = weight + ((size_t)(k * 256 + cout) * 256 + cin) * 9;
#pragma unroll
        for (int tp = 0; tp < 9; ++tp) w[k][tp] = wp[tp];
    }
    int ch = cout >> 7, coutl = cout & 127;
    int cing = cr >> 3, cinr = cr & 7;
    for (int b = 0; b < BB; ++b) {
        float a0 = s_attn[b * 4 + 0], a1 = s_attn[b * 4 + 1];
        float a2 = s_attn[b * 4 + 2], a3 = s_attn[b * 4 + 3];
#pragma unroll
        for (int tap = 0; tap < 9; ++tap) {
            float v = a0 * w[0][tap] + a1 * w[1][tap] + a2 * w[2][tap] + a3 * w[3][tap];
            size_t e = (size_t)((b * 2 + ch) * 8 + cb8) * 36864 +
                       (tap * 4 + cing) * 1024 + coutl * 8 + cinr;
            aggw[e] = (__bf16)v;
        }
    }
}

// ---------- 4. x -> padded NHWC bf16 (interior, tiled transpose) ----------
__global__ void xpad_int_k(const float* __restrict__ x, __bf16* __restrict__ xpad) {
    __shared__ float tile[64][65];
    int pt = blockIdx.x;      // 0..48 pixel tile (64 px)
    int cg = blockIdx.y;      // 0..3 cin group (64 cins)
    int b  = blockIdx.z;
    int q = threadIdx.x >> 6, l = threadIdx.x & 63;
    for (int k = 0; k < 16; ++k) {
        int cl = q * 16 + k;
        tile[cl][l] = x[((size_t)(b * 256 + cg * 64 + cl)) * NPIX + pt * 64 + l];
    }
    __syncthreads();
    for (int k = 0; k < 16; ++k) {
        int pl = q * 16 + k;
        int pixel = pt * 64 + pl;
        int h = pixel / 56, w = pixel - h * 56;
        xpad[(((size_t)b * PPIX + (h + 1) * 58 + (w + 1)) * 256) + cg * 64 + l] =
            (__bf16)tile[l][pl];
    }
}

// ---------- 5. conv: implicit GEMM, 3-sub-step deep-pipelined schedule ----------
// block: 128 couts x 8 output rows; 8 waves, wave = 128 couts x 1 row (Mr=8, Nr=4).
// LDS: X dbuf 2x40KB ([cg4][row10][col64][16B]) + A 73.7KB in 3 thirds of 3 taps.
// Per cb8 K-step: 3 sub-steps of 3 taps (96 MFMA/wave). Every staged buffer is
// issued >= 2 sub-steps (~7000 cyc) before first read; vmcnt never 0 in steady
// state (8/8/3); one raw s_barrier + sched_barrier per sub-step.
__global__ __launch_bounds__(512, 2) void conv_k(const __bf16* __restrict__ xpad,
                                                 const __bf16* __restrict__ aggw,
                                                 const float* __restrict__ aggb,
                                                 float* __restrict__ out) {
    extern __shared__ __attribute__((aligned(16))) char smem[];
    char* xs = smem;                 // 2 X buffers
    char* as = smem + 2 * XBUF;      // A buffer (3 thirds of 24KB)

    const int orig = blockIdx.x;
    const int logical = (orig & 7) * 28 + (orig >> 3);   // bijective, 224 = 8*28
    const int b  = logical / 14;
    const int r  = logical - b * 14;
    const int rp = r >> 1;            // 0..6 row-octet
    const int ch = r & 1;             // cout half
    const int tid = threadIdx.x;
    const int wid = tid >> 6, lane = tid & 63;
    const int l15 = lane & 15, l4 = lane >> 4;
    const int h0 = rp * 8;            // top padded row staged (rows h0..h0+9)

    const char* xb  = (const char*)xpad + (size_t)b * PPIX * 512;
    const char* awb = (const char*)aggw + (size_t)((b * 2 + ch) * 8) * ABUF;

    f32x4 acc[8][4];
#pragma unroll
    for (int m = 0; m < 8; ++m)
#pragma unroll
        for (int n = 0; n < 4; ++n) acc[m][n] = (f32x4){0.f, 0.f, 0.f, 0.f};

    // stage X K-block c into buffer buf: 40 x 1KB, 5 per wave
    auto XSTAGE = [&](int buf, int c) {
#pragma unroll
        for (int j = 0; j < 5; ++j) {
            int k = wid * 5 + j;             // 0..39
            int cg = k / 10, row = k - cg * 10;
            const char* src = xb + (size_t)((h0 + row) * 58 + lane) * 512 + c * 64 + cg * 16;
            __builtin_amdgcn_global_load_lds(
                (const __attribute__((address_space(1))) void*)src,
                (__attribute__((address_space(3))) void*)(xs + buf * XBUF + k * 1024),
                16, 0, 0);
        }
    };
    // stage A third (taps 3*third..3*third+2) of K-block c: 24 x 1KB, 3 per wave
    auto ASTAGE3 = [&](int third, int c) {
#pragma unroll
        for (int j = 0; j < 3; ++j) {
            int k = third * 24 + wid * 3 + j;
            const char* src = awb + (size_t)c * ABUF + k * 1024 + lane * 16;
            __builtin_amdgcn_global_load_lds(
                (const __attribute__((address_space(1))) void*)src,
                (__attribute__((address_space(3))) void*)(as + k * 1024),
                16, 0, 0);
        }
    };
    // compute taps t0..t0+2 against X buffer base lb
    auto TAP3 = [&](int t0, const char* lb) {
#pragma unroll
        for (int tt = 0; tt < 3; ++tt) {
            int t = t0 + tt;
            int kh = t / 3, kw = t - kh * 3;
            bf16x8 a[8];
#pragma unroll
            for (int m = 0; m < 8; ++m)
                a[m] = *(const bf16x8*)(as + (t * 4 + l4) * 2048 + (m * 16 + l15) * 16);
#pragma unroll
            for (int nf = 0; nf < 4; ++nf) {
                bf16x8 bb = *(const bf16x8*)(lb +
                    (((l4 * 10 + wid + kh) * 64) + nf * 16 + l15 + kw) * 16);
#pragma unroll
                for (int m = 0; m < 8; ++m)
                    acc[m][nf] = __builtin_amdgcn_mfma_f32_16x16x32_bf16(a[m], bb, acc[m][nf], 0, 0, 0);
            }
        }
    };

#define SUBBAR(N) do { \
        asm volatile("s_waitcnt vmcnt(" #N ")" ::: "memory"); \
        __builtin_amdgcn_s_barrier(); \
        __builtin_amdgcn_sched_barrier(0); } while (0)

    // prologue: X(0), A-thirds 0,1 of step 0; A1(0) may stay in flight
    XSTAGE(0, 0);
    ASTAGE3(0, 0);
    ASTAGE3(1, 0);
    SUBBAR(3);

    int cur = 0;
    for (int c = 0; c < 7; ++c) {
        const char* lb = xs + cur * XBUF;
        // sub0: taps 0-2 (A0(c)); issue A2(c) + X(c+1)
        ASTAGE3(2, c);
        XSTAGE(cur ^ 1, c + 1);
        __builtin_amdgcn_s_setprio(1); TAP3(0, lb); __builtin_amdgcn_s_setprio(0);
        SUBBAR(8);                        // A1(c) landed; A2+X stay in flight
        // sub1: taps 3-5 (A1(c)); issue A0(c+1)
        ASTAGE3(0, c + 1);
        __builtin_amdgcn_s_setprio(1); TAP3(3, lb); __builtin_amdgcn_s_setprio(0);
        SUBBAR(8);                        // A2(c) landed; X+A0 stay in flight
        // sub2: taps 6-8 (A2(c)); issue A1(c+1)
        ASTAGE3(1, c + 1);
        __builtin_amdgcn_s_setprio(1); TAP3(6, lb); __builtin_amdgcn_s_setprio(0);
        SUBBAR(3);                        // X(c+1)+A0(c+1) landed; A1(c+1) in flight
        cur ^= 1;
    }
    {   // step 7 (peeled, no next-step staging)
        const char* lb = xs + cur * XBUF;
        ASTAGE3(2, 7);
        __builtin_amdgcn_s_setprio(1); TAP3(0, lb); __builtin_amdgcn_s_setprio(0);
        SUBBAR(3);                        // A1(7) landed
        __builtin_amdgcn_s_setprio(1); TAP3(3, lb); __builtin_amdgcn_s_setprio(0);
        SUBBAR(0);                        // A2(7) landed
        __builtin_amdgcn_s_setprio(1); TAP3(6, lb); __builtin_amdgcn_s_setprio(0);
    }
#undef SUBBAR

    const int row = rp * 8 + wid;             // output row
#pragma unroll
    for (int m = 0; m < 8; ++m) {
#pragma unroll
        for (int i = 0; i < 4; ++i) {
            int cout = ch * 128 + m * 16 + l4 * 4 + i;
            float bv = aggb[b * COUTC + cout];
            float* op = out + ((size_t)(b * COUTC + cout) * NPIX + row * 56);
#pragma unroll
            for (int nf = 0; nf < 3; ++nf)
                __builtin_nontemporal_store(acc[m][nf][i] + bv, op + nf * 16 + l15);
            if (l15 < 8)
                __builtin_nontemporal_store(acc[m][3][i] + bv, op + 48 + l15);
        }
    }
}

extern "C" void kernel_launch(void* const* d_in, const int* in_sizes, int n_in,
                              void* d_out, int out_size, void* d_ws, size_t ws_size,
                              hipStream_t stream) {
    (void)in_sizes; (void)n_in; (void)out_size; (void)ws_size;
    const float* ref    = (const float*)d_in[0];
    const float* x      = (const float*)d_in[1];
    const float* fc1w   = (const float*)d_in[2];
    const float* fc2w   = (const float*)d_in[3];
    const float* fc2b   = (const float*)d_in[4];
    const float* weight = (const float*)d_in[5];
    const float* bias   = (const float*)d_in[6];
    float* out = (float*)d_out;
    char* ws = (char*)d_ws;

    float*  attn   = (float*)(ws + WS_ATTN);
    float*  aggb   = (float*)(ws + WS_AGGB);
    float*  pooled = (float*)(ws + WS_POOL);
    __bf16* aggw   = (__bf16*)(ws + WS_AGGW);
    __bf16* xpad   = (__bf16*)(ws + WS_XPAD);

    // allow >64KB dynamic LDS for conv_k (deterministic, capture-safe host call)
    hipFuncSetAttribute((const void*)conv_k,
                        hipFuncAttributeMaxDynamicSharedMemorySize, LDS_TOT);

    pool_k<<<1024, 256, 0, stream>>>(ref, pooled, xpad);
    attn_k<<<16, 256, 0, stream>>>(pooled, fc1w, fc2w, fc2b, bias, attn, aggb);
    aggw_k<<<dim3(32, 8), 256, 0, stream>>>(attn, weight, aggw);
    xpad_int_k<<<dim3(49, 4, 16), 256, 0, stream>>>(x, xpad);
    conv_k<<<224, 512, LDS_TOT, stream>>>(xpad, aggw, aggb, out);
}